// Round 1
// baseline (399.404 us; speedup 1.0000x reference)
//
#include <hip/hip_runtime.h>
#include <hip/hip_bf16.h>

#define BSZ  8
#define LSEQ 8192
#define DDIM 256
#define HDIM 1024
#define MFFT 4096   // half-size complex FFT length (N = 8192 real)

typedef __bf16 bf16;
typedef __bf16 bf16x8 __attribute__((ext_vector_type(8)));
typedef __bf16 bf16x4 __attribute__((ext_vector_type(4)));
typedef float  f32x4  __attribute__((ext_vector_type(4)));

__device__ __forceinline__ void wave_reduce2(float& a, float& b) {
    #pragma unroll
    for (int off = 1; off < 64; off <<= 1) {
        a += __shfl_xor(a, off);
        b += __shfl_xor(b, off);
    }
}

// ---------------- K0: bf16-transpose weights: W1T[h][d], W2T[d][h] ----------
__global__ __launch_bounds__(256) void k0_prep(const float* __restrict__ w1,
                                               const float* __restrict__ w2,
                                               bf16* __restrict__ w1t,
                                               bf16* __restrict__ w2t) {
    const int e = blockIdx.x * 256 + threadIdx.x;   // 0..262143
    {   // W1T[h][d] = w1[d][h]
        const int h = e >> 8, d = e & 255;
        w1t[e] = (bf16)w1[d * HDIM + h];
    }
    {   // W2T[d][h] = w2[h][d]
        const int d = e >> 10, h = e & 1023;
        w2t[e] = (bf16)w2[h * DDIM + d];
    }
}

// ---------------- K1: LN1 + ReLU + eps, transposed write: ht(B,D,L) --------
__global__ __launch_bounds__(256) void k1_ln1_relu_T(const float* __restrict__ x,
                                                     const float* __restrict__ g1,
                                                     const float* __restrict__ b1,
                                                     float* __restrict__ ht) {
    __shared__ float tile[DDIM][33];   // [d][l] padded
    const int tid  = threadIdx.x;
    const int wave = tid >> 6, lane = tid & 63;
    const int b  = blockIdx.x >> 8;           // 256 l-tiles per batch
    const int l0 = (blockIdx.x & 255) << 5;
    const float4 g4 = *(const float4*)&g1[lane * 4];
    const float4 b4 = *(const float4*)&b1[lane * 4];
    for (int r8 = 0; r8 < 8; ++r8) {
        const int l = r8 * 4 + wave;
        const float4 v = *(const float4*)&x[(b * LSEQ + l0 + l) * DDIM + lane * 4];
        float s = v.x + v.y + v.z + v.w;
        float q = v.x * v.x + v.y * v.y + v.z * v.z + v.w * v.w;
        wave_reduce2(s, q);
        const float mean = s * (1.0f / 256.0f);
        const float var  = q * (1.0f / 256.0f) - mean * mean;
        const float rstd = rsqrtf(var + 1e-5f);
        const float vv[4] = {v.x, v.y, v.z, v.w};
        const float gg[4] = {g4.x, g4.y, g4.z, g4.w};
        const float bb[4] = {b4.x, b4.y, b4.z, b4.w};
        #pragma unroll
        for (int j = 0; j < 4; ++j) {
            float t = (vv[j] - mean) * rstd * gg[j] + bb[j];
            t = fmaxf(t, 0.0f) + 1e-6f;
            tile[lane * 4 + j][l] = t;
        }
    }
    __syncthreads();
    for (int i = tid; i < DDIM * 32; i += 256) {
        const int d = i >> 5, ll = i & 31;
        ht[(b * DDIM + d) * LSEQ + l0 + ll] = tile[d][ll];
    }
}

// ---------------- K2: per-channel SPSD1D (rfft -> local-max filter -> irfft)
__device__ __forceinline__ void fft_core(float2* Z, int tid, float dir) {
    // dir=+1: forward (twiddle e^{-2pi i j/m}); dir=-1: inverse (unnormalized)
    for (int mm = MFFT; mm >= 2; mm >>= 1) {
        const int   half = mm >> 1;
        const float unit = dir * (-6.28318530717958647692f) / (float)mm;
        for (int it = 0; it < 8; ++it) {           // 2048 butterflies/stage
            const int i = tid + (it << 8);
            const int j = i & (half - 1);
            const int base = (i << 1) - j;
            const float2 u = Z[base], v = Z[base + half];
            Z[base] = make_float2(u.x + v.x, u.y + v.y);
            const float dx = u.x - v.x, dy = u.y - v.y;
            float sn, cs;
            __sincosf(unit * (float)j, &sn, &cs);
            Z[base + half] = make_float2(dx * cs - dy * sn, dx * sn + dy * cs);
        }
        __syncthreads();
    }
    // bit-reverse (12 bit), disjoint pair swaps
    for (int i = tid; i < MFFT; i += 256) {
        const int r = (int)(__brev((unsigned)i) >> 20);
        if (r > i) { float2 t = Z[i]; Z[i] = Z[r]; Z[r] = t; }
    }
    __syncthreads();
}

__global__ __launch_bounds__(256) void k2_spsd(float* __restrict__ ht) {
    __shared__ float2 Z[MFFT];        // 32 KB
    __shared__ float  mag[MFFT + 8];  // 4097 used
    const int tid = threadIdx.x;
    float* row = ht + (size_t)blockIdx.x * LSEQ;

    for (int m = tid; m < MFFT; m += 256)
        Z[m] = *(const float2*)&row[2 * m];
    __syncthreads();

    fft_core(Z, tid, 1.0f);           // forward FFT of packed even+i*odd

    // Pass A: magnitudes of rfft bins 0..4096
    for (int k = tid; k <= MFFT; k += 256) {
        const int ka = k & (MFFT - 1);
        const int kb = (MFFT - k) & (MFFT - 1);
        const float2 A = Z[ka], Bc = Z[kb];
        const float zex = 0.5f * (A.x + Bc.x), zey = 0.5f * (A.y - Bc.y);
        const float zox = 0.5f * (A.y + Bc.y), zoy = -0.5f * (A.x - Bc.x);
        float sn, cs;   // e^{-i pi k/4096} = (cs, sn)
        __sincosf((float)k * (-3.14159265358979323846f / 4096.0f), &sn, &cs);
        const float xr = zex + zox * cs - zoy * sn;
        const float xi = zey + zox * sn + zoy * cs;
        mag[k] = sqrtf(xr * xr + xi * xi);
    }
    __syncthreads();

    // Pass B: mask + rebuild filtered half-spectrum, in place (pairs disjoint)
    for (int k = tid; k <= 2048; k += 256) {
        const int km = (MFFT - k) & (MFFT - 1);
        const float2 Pk = Z[k];
        const float2 Pm = Z[km];
        float sn, cs;   // theta = pi k/4096
        __sincosf((float)k * (3.14159265358979323846f / 4096.0f), &sn, &cs);
        // bin k:  W = (cs,-sn)
        const float zex = 0.5f * (Pk.x + Pm.x), zey = 0.5f * (Pk.y - Pm.y);
        const float zox = 0.5f * (Pk.y + Pm.y), zoy = -0.5f * (Pk.x - Pm.x);
        float xkr = zex + zox * cs + zoy * sn;
        float xki = zey - zox * sn + zoy * cs;
        // bin 4096-k:  A'=Pm, B'=conj(Pk), W = (-cs,-sn)
        const float zex2 = 0.5f * (Pm.x + Pk.x), zey2 = 0.5f * (Pm.y - Pk.y);
        const float zox2 = 0.5f * (Pm.y + Pk.y), zoy2 = -0.5f * (Pm.x - Pk.x);
        float xmr = zex2 - zox2 * cs + zoy2 * sn;
        float xmi = zey2 - zox2 * sn - zoy2 * cs;
        // keep masks: local max over window [j-3, j+4] (clamped), or j < 3
        const int jm = MFFT - k;
        bool keepk, keepm;
        {
            const int lo = (k - 3 < 0) ? 0 : k - 3;
            const int hi = (k + 4 > 4096) ? 4096 : k + 4;
            float mx = mag[k];
            for (int t2 = lo; t2 <= hi; ++t2) mx = fmaxf(mx, mag[t2]);
            keepk = (k < 3) || (mag[k] >= mx);
        }
        {
            const int hi = (jm + 4 > 4096) ? 4096 : jm + 4;
            float mx = mag[jm];
            for (int t2 = jm - 3; t2 <= hi; ++t2) mx = fmaxf(mx, mag[t2]);
            keepm = (mag[jm] >= mx);
        }
        if (!keepk) { xkr = 0.0f; xki = 0.0f; }
        if (!keepm) { xmr = 0.0f; xmi = 0.0f; }
        // Z'f[k] = Ze' + i Zo';  Ze' = (X'k + conj(X'm))/2,  Zo' = (cs,sn)*(X'k - conj(X'm))/2
        const float zpex = 0.5f * (xkr + xmr), zpey = 0.5f * (xki - xmi);
        const float dfx  = 0.5f * (xkr - xmr), dfy  = 0.5f * (xki + xmi);
        const float zpox = dfx * cs - dfy * sn, zpoy = dfx * sn + dfy * cs;
        const float2 zk = make_float2(zpex - zpoy, zpey + zpox);
        // Z'f[4096-k]:  t = (-cs, sn)
        const float zex3 = 0.5f * (xmr + xkr), zey3 = 0.5f * (xmi - xki);
        const float df2x = 0.5f * (xmr - xkr), df2y = 0.5f * (xmi + xki);
        const float zo3x = -df2x * cs - df2y * sn, zo3y = df2x * sn - df2y * cs;
        const float2 zm = make_float2(zex3 - zo3y, zey3 + zo3x);
        Z[k] = zk;
        if (k != 0 && k != 2048) Z[MFFT - k] = zm;
    }
    __syncthreads();

    fft_core(Z, tid, -1.0f);          // inverse (unnormalized)

    const float invM = 1.0f / (float)MFFT;
    for (int m = tid; m < MFFT; m += 256) {
        const float2 z = Z[m];
        *(float2*)&row[2 * m] = make_float2(z.x * invM, z.y * invM);
    }
}

// ---------------- K3: transpose back * filt_w, LN2, cast bf16 --------------
__global__ __launch_bounds__(256) void k3_filt_ln2(const float* __restrict__ ht,
                                                   const float* __restrict__ fw,
                                                   const float* __restrict__ g2,
                                                   const float* __restrict__ b2,
                                                   bf16* __restrict__ aln) {
    __shared__ float tile[DDIM][33];
    const int tid  = threadIdx.x;
    const int wave = tid >> 6, lane = tid & 63;
    const int b  = blockIdx.x >> 8;
    const int l0 = (blockIdx.x & 255) << 5;
    for (int i = tid; i < DDIM * 32; i += 256) {
        const int d = i >> 5, ll = i & 31;
        tile[d][ll] = ht[(b * DDIM + d) * LSEQ + l0 + ll];
    }
    __syncthreads();
    const float4 g4 = *(const float4*)&g2[lane * 4];
    const float4 bb4 = *(const float4*)&b2[lane * 4];
    for (int r8 = 0; r8 < 8; ++r8) {
        const int l = r8 * 4 + wave;
        const int gl = l0 + l;
        const float4 f4 = *(const float4*)&fw[gl * DDIM + lane * 4];
        float v[4];
        v[0] = tile[lane * 4 + 0][l] * f4.x;
        v[1] = tile[lane * 4 + 1][l] * f4.y;
        v[2] = tile[lane * 4 + 2][l] * f4.z;
        v[3] = tile[lane * 4 + 3][l] * f4.w;
        float s = v[0] + v[1] + v[2] + v[3];
        float q = v[0] * v[0] + v[1] * v[1] + v[2] * v[2] + v[3] * v[3];
        wave_reduce2(s, q);
        const float mean = s * (1.0f / 256.0f);
        const float var  = q * (1.0f / 256.0f) - mean * mean;
        const float rstd = rsqrtf(var + 1e-5f);
        const float gg[4] = {g4.x, g4.y, g4.z, g4.w};
        const float bb[4] = {bb4.x, bb4.y, bb4.z, bb4.w};
        bf16x4 o;
        #pragma unroll
        for (int j = 0; j < 4; ++j)
            o[j] = (bf16)((v[j] - mean) * rstd * gg[j] + bb[j]);
        *(bf16x4*)&aln[(b * LSEQ + gl) * DDIM + lane * 4] = o;
    }
}

// ---------------- K4: fused MLP (gelu exact) + bias + residual -------------
__global__ __launch_bounds__(256) void k4_mlp(const bf16* __restrict__ aln,
                                              const bf16* __restrict__ w1t,
                                              const bf16* __restrict__ w2t,
                                              const float* __restrict__ bb1,
                                              const float* __restrict__ bb2,
                                              const float* __restrict__ x,
                                              float* __restrict__ out) {
    __shared__ __align__(16) bf16 lA[32 * 264];   // A tile   [32][264]
    __shared__ __align__(16) bf16 lW[256 * 72];   // W strip  (reused, padded)
    __shared__ __align__(16) bf16 lM[32 * 72];    // gelu(M)  [32][72]
    const int tid  = threadIdx.x;
    const int lane = tid & 63, wave = tid >> 6;
    const int rowLane = lane & 15, grp = lane >> 4;
    const int mt = wave & 1, nq = wave >> 1;
    const int row0 = blockIdx.x << 5;

    #pragma unroll
    for (int it = 0; it < 4; ++it) {              // stage A tile (32x256 bf16)
        const int idx = tid + (it << 8);
        const int r = idx >> 5, c8 = idx & 31;
        *(uint4*)&lA[r * 264 + c8 * 8] = *(const uint4*)&aln[(row0 + r) * DDIM + c8 * 8];
    }
    f32x4 acc2[8];
    #pragma unroll
    for (int i = 0; i < 8; ++i) acc2[i] = (f32x4){0.f, 0.f, 0.f, 0.f};

    for (int c = 0; c < 16; ++c) {                // H chunks of 64
        __syncthreads();                          // lA ready / lW free
        #pragma unroll
        for (int it = 0; it < 8; ++it) {          // W1T strip [64][264]
            const int idx = tid + (it << 8);
            const int r = idx >> 5, c8 = idx & 31;
            *(uint4*)&lW[r * 264 + c8 * 8] = *(const uint4*)&w1t[(c * 64 + r) * DDIM + c8 * 8];
        }
        __syncthreads();
        #pragma unroll
        for (int n = 0; n < 2; ++n) {             // GEMM1 -> gelu -> lM
            f32x4 a1 = {0.f, 0.f, 0.f, 0.f};
            const int hcol = nq * 32 + n * 16 + rowLane;
            #pragma unroll
            for (int ks = 0; ks < 8; ++ks) {
                const bf16x8 aF = *(const bf16x8*)&lA[(mt * 16 + rowLane) * 264 + ks * 32 + grp * 8];
                const bf16x8 bF = *(const bf16x8*)&lW[hcol * 264 + ks * 32 + grp * 8];
                a1 = __builtin_amdgcn_mfma_f32_16x16x32_bf16(aF, bF, a1, 0, 0, 0);
            }
            const float bias = bb1[c * 64 + hcol];
            #pragma unroll
            for (int j = 0; j < 4; ++j) {
                const float vv = a1[j] + bias;
                const float ge = 0.5f * vv * (1.0f + erff(vv * 0.70710678118654752f));
                lM[(mt * 16 + grp * 4 + j) * 72 + hcol] = (bf16)ge;
            }
        }
        __syncthreads();                          // GEMM1 done with lW, lM full
        #pragma unroll
        for (int it = 0; it < 8; ++it) {          // W2T strip [256][72]
            const int idx = tid + (it << 8);
            const int r = idx >> 3, c8 = idx & 7;
            *(uint4*)&lW[r * 72 + c8 * 8] = *(const uint4*)&w2t[r * HDIM + c * 64 + c8 * 8];
        }
        __syncthreads();
        #pragma unroll
        for (int n2 = 0; n2 < 8; ++n2) {          // GEMM2 accumulate
            const int dcol = nq * 128 + n2 * 16 + rowLane;
            #pragma unroll
            for (int ks = 0; ks < 2; ++ks) {
                const bf16x8 aF = *(const bf16x8*)&lM[(mt * 16 + rowLane) * 72 + ks * 32 + grp * 8];
                const bf16x8 bF = *(const bf16x8*)&lW[dcol * 72 + ks * 32 + grp * 8];
                acc2[n2] = __builtin_amdgcn_mfma_f32_16x16x32_bf16(aF, bF, acc2[n2], 0, 0, 0);
            }
        }
    }
    #pragma unroll
    for (int n2 = 0; n2 < 8; ++n2) {              // epilogue: +bb2 + residual
        const int dcol = nq * 128 + n2 * 16 + rowLane;
        const float bias2 = bb2[dcol];
        #pragma unroll
        for (int j = 0; j < 4; ++j) {
            const int r = mt * 16 + grp * 4 + j;
            const int gidx = (row0 + r) * DDIM + dcol;
            out[gidx] = acc2[n2][j] + bias2 + x[gidx];
        }
    }
}

extern "C" void kernel_launch(void* const* d_in, const int* in_sizes, int n_in,
                              void* d_out, int out_size, void* d_ws, size_t ws_size,
                              hipStream_t stream) {
    (void)in_sizes; (void)n_in; (void)out_size; (void)ws_size;
    const float* x   = (const float*)d_in[0];
    const float* g1  = (const float*)d_in[1];
    const float* b1  = (const float*)d_in[2];
    const float* g2  = (const float*)d_in[3];
    const float* b2  = (const float*)d_in[4];
    const float* fw  = (const float*)d_in[5];
    const float* w1  = (const float*)d_in[6];
    const float* bb1 = (const float*)d_in[7];
    const float* w2  = (const float*)d_in[8];
    const float* bb2 = (const float*)d_in[9];
    float* out = (float*)d_out;
    char*  ws  = (char*)d_ws;

    bf16* aln = (bf16*)ws;                               // 33554432 B
    bf16* w1t = (bf16*)(ws + (size_t)33554432);          //   524288 B
    bf16* w2t = (bf16*)(ws + (size_t)34078720);          //   524288 B
    float* ht = out;                                     // reuse d_out as (B,D,L) scratch

    k0_prep<<<dim3(1024), dim3(256), 0, stream>>>(w1, w2, w1t, w2t);
    k1_ln1_relu_T<<<dim3(2048), dim3(256), 0, stream>>>(x, g1, b1, ht);
    k2_spsd<<<dim3(2048), dim3(256), 0, stream>>>(ht);
    k3_filt_ln2<<<dim3(2048), dim3(256), 0, stream>>>(ht, fw, g2, b2, aln);
    k4_mlp<<<dim3(2048), dim3(256), 0, stream>>>(aln, w1t, w2t, bb1, bb2, x, out);
}

// Round 2
// 315.624 us; speedup vs baseline: 1.2654x; 1.2654x over previous
//
#include <hip/hip_runtime.h>
#include <hip/hip_bf16.h>

#define BSZ  8
#define LSEQ 8192
#define DDIM 256
#define HDIM 1024
#define MFFT 4096   // half-size complex FFT length (N = 8192 real)

typedef __bf16 bf16;
typedef __bf16 bf16x8 __attribute__((ext_vector_type(8)));
typedef __bf16 bf16x4 __attribute__((ext_vector_type(4)));
typedef float  f32x4  __attribute__((ext_vector_type(4)));

__device__ __forceinline__ void wave_reduce2(float& a, float& b) {
    #pragma unroll
    for (int off = 1; off < 64; off <<= 1) {
        a += __shfl_xor(a, off);
        b += __shfl_xor(b, off);
    }
}

// async global->LDS 16B; LDS dest = wave-uniform base + lane*16 (linear).
// AS casts via integer round-trip (low 32 bits of generic LDS ptr == AS(3) addr).
__device__ __forceinline__ void gl_lds16(const void* g, void* l) {
    __builtin_amdgcn_global_load_lds(
        (const __attribute__((address_space(1))) unsigned int*)(unsigned long long)g,
        (__attribute__((address_space(3))) unsigned int*)(unsigned int)(unsigned long long)l,
        16, 0, 0);
}

// ---------------- K0: bf16 weights: W1T[h][d]; W2C chunk-major [c][d][hh] ---
__global__ __launch_bounds__(256) void k0_prep(const float* __restrict__ w1,
                                               const float* __restrict__ w2,
                                               bf16* __restrict__ w1t,
                                               bf16* __restrict__ w2ct) {
    const int e = blockIdx.x * 256 + threadIdx.x;   // 0..262143
    {   // W1T[h][d] = w1[d][h]
        const int h = e >> 8, d = e & 255;
        w1t[e] = (bf16)w1[d * HDIM + h];
    }
    {   // W2C[c][d][hh] = w2[c*64+hh][d]
        const int hh = e & 63, d = (e >> 6) & 255, c = e >> 14;
        w2ct[e] = (bf16)w2[(c * 64 + hh) * DDIM + d];
    }
}

// ---------------- K1: LN1 + ReLU + eps, transposed write: ht(B,D,L) --------
__global__ __launch_bounds__(256) void k1_ln1_relu_T(const float* __restrict__ x,
                                                     const float* __restrict__ g1,
                                                     const float* __restrict__ b1,
                                                     float* __restrict__ ht) {
    __shared__ float tile[DDIM][33];   // [d][l] padded
    const int tid  = threadIdx.x;
    const int wave = tid >> 6, lane = tid & 63;
    const int b  = blockIdx.x >> 8;           // 256 l-tiles per batch
    const int l0 = (blockIdx.x & 255) << 5;
    const float4 g4 = *(const float4*)&g1[lane * 4];
    const float4 b4 = *(const float4*)&b1[lane * 4];
    for (int r8 = 0; r8 < 8; ++r8) {
        const int l = r8 * 4 + wave;
        const float4 v = *(const float4*)&x[(b * LSEQ + l0 + l) * DDIM + lane * 4];
        float s = v.x + v.y + v.z + v.w;
        float q = v.x * v.x + v.y * v.y + v.z * v.z + v.w * v.w;
        wave_reduce2(s, q);
        const float mean = s * (1.0f / 256.0f);
        const float var  = q * (1.0f / 256.0f) - mean * mean;
        const float rstd = rsqrtf(var + 1e-5f);
        const float vv[4] = {v.x, v.y, v.z, v.w};
        const float gg[4] = {g4.x, g4.y, g4.z, g4.w};
        const float bb[4] = {b4.x, b4.y, b4.z, b4.w};
        #pragma unroll
        for (int j = 0; j < 4; ++j) {
            float t = (vv[j] - mean) * rstd * gg[j] + bb[j];
            t = fmaxf(t, 0.0f) + 1e-6f;
            tile[lane * 4 + j][l] = t;
        }
    }
    __syncthreads();
    for (int i = tid; i < DDIM * 32; i += 256) {
        const int d = i >> 5, ll = i & 31;
        ht[(b * DDIM + d) * LSEQ + l0 + ll] = tile[d][ll];
    }
}

// ---------------- K2: per-channel SPSD1D (rfft -> local-max filter -> irfft)
__device__ __forceinline__ void fft_core(float2* Z, int tid, float dir) {
    // dir=+1: forward (twiddle e^{-2pi i j/m}); dir=-1: inverse (unnormalized)
    for (int mm = MFFT; mm >= 2; mm >>= 1) {
        const int   half = mm >> 1;
        const float unit = dir * (-6.28318530717958647692f) / (float)mm;
        for (int it = 0; it < 8; ++it) {           // 2048 butterflies/stage
            const int i = tid + (it << 8);
            const int j = i & (half - 1);
            const int base = (i << 1) - j;
            const float2 u = Z[base], v = Z[base + half];
            Z[base] = make_float2(u.x + v.x, u.y + v.y);
            const float dx = u.x - v.x, dy = u.y - v.y;
            float sn, cs;
            __sincosf(unit * (float)j, &sn, &cs);
            Z[base + half] = make_float2(dx * cs - dy * sn, dx * sn + dy * cs);
        }
        __syncthreads();
    }
    // bit-reverse (12 bit), disjoint pair swaps
    for (int i = tid; i < MFFT; i += 256) {
        const int r = (int)(__brev((unsigned)i) >> 20);
        if (r > i) { float2 t = Z[i]; Z[i] = Z[r]; Z[r] = t; }
    }
    __syncthreads();
}

__global__ __launch_bounds__(256) void k2_spsd(float* __restrict__ ht) {
    __shared__ float2 Z[MFFT];        // 32 KB
    __shared__ float  mag[MFFT + 8];  // 4097 used
    const int tid = threadIdx.x;
    float* row = ht + (size_t)blockIdx.x * LSEQ;

    for (int m = tid; m < MFFT; m += 256)
        Z[m] = *(const float2*)&row[2 * m];
    __syncthreads();

    fft_core(Z, tid, 1.0f);           // forward FFT of packed even+i*odd

    // Pass A: magnitudes of rfft bins 0..4096
    for (int k = tid; k <= MFFT; k += 256) {
        const int ka = k & (MFFT - 1);
        const int kb = (MFFT - k) & (MFFT - 1);
        const float2 A = Z[ka], Bc = Z[kb];
        const float zex = 0.5f * (A.x + Bc.x), zey = 0.5f * (A.y - Bc.y);
        const float zox = 0.5f * (A.y + Bc.y), zoy = -0.5f * (A.x - Bc.x);
        float sn, cs;   // e^{-i pi k/4096} = (cs, sn)
        __sincosf((float)k * (-3.14159265358979323846f / 4096.0f), &sn, &cs);
        const float xr = zex + zox * cs - zoy * sn;
        const float xi = zey + zox * sn + zoy * cs;
        mag[k] = sqrtf(xr * xr + xi * xi);
    }
    __syncthreads();

    // Pass B: mask + rebuild filtered half-spectrum, in place (pairs disjoint)
    for (int k = tid; k <= 2048; k += 256) {
        const int km = (MFFT - k) & (MFFT - 1);
        const float2 Pk = Z[k];
        const float2 Pm = Z[km];
        float sn, cs;   // theta = pi k/4096
        __sincosf((float)k * (3.14159265358979323846f / 4096.0f), &sn, &cs);
        // bin k:  W = (cs,-sn)
        const float zex = 0.5f * (Pk.x + Pm.x), zey = 0.5f * (Pk.y - Pm.y);
        const float zox = 0.5f * (Pk.y + Pm.y), zoy = -0.5f * (Pk.x - Pm.x);
        float xkr = zex + zox * cs + zoy * sn;
        float xki = zey - zox * sn + zoy * cs;
        // bin 4096-k:  A'=Pm, B'=conj(Pk), W = (-cs,-sn)
        const float zex2 = 0.5f * (Pm.x + Pk.x), zey2 = 0.5f * (Pm.y - Pk.y);
        const float zox2 = 0.5f * (Pm.y + Pk.y), zoy2 = -0.5f * (Pm.x - Pk.x);
        float xmr = zex2 - zox2 * cs + zoy2 * sn;
        float xmi = zey2 - zox2 * sn - zoy2 * cs;
        // keep masks: local max over window [j-3, j+4] (clamped), or j < 3
        const int jm = MFFT - k;
        bool keepk, keepm;
        {
            const int lo = (k - 3 < 0) ? 0 : k - 3;
            const int hi = (k + 4 > 4096) ? 4096 : k + 4;
            float mx = mag[k];
            for (int t2 = lo; t2 <= hi; ++t2) mx = fmaxf(mx, mag[t2]);
            keepk = (k < 3) || (mag[k] >= mx);
        }
        {
            const int hi = (jm + 4 > 4096) ? 4096 : jm + 4;
            float mx = mag[jm];
            for (int t2 = jm - 3; t2 <= hi; ++t2) mx = fmaxf(mx, mag[t2]);
            keepm = (mag[jm] >= mx);
        }
        if (!keepk) { xkr = 0.0f; xki = 0.0f; }
        if (!keepm) { xmr = 0.0f; xmi = 0.0f; }
        // Z'f[k] = Ze' + i Zo';  Ze' = (X'k + conj(X'm))/2,  Zo' = (cs,sn)*(X'k - conj(X'm))/2
        const float zpex = 0.5f * (xkr + xmr), zpey = 0.5f * (xki - xmi);
        const float dfx  = 0.5f * (xkr - xmr), dfy  = 0.5f * (xki + xmi);
        const float zpox = dfx * cs - dfy * sn, zpoy = dfx * sn + dfy * cs;
        const float2 zk = make_float2(zpex - zpoy, zpey + zpox);
        // Z'f[4096-k]:  t = (-cs, sn)
        const float zex3 = 0.5f * (xmr + xkr), zey3 = 0.5f * (xmi - xki);
        const float df2x = 0.5f * (xmr - xkr), df2y = 0.5f * (xmi + xki);
        const float zo3x = -df2x * cs - df2y * sn, zo3y = df2x * sn - df2y * cs;
        const float2 zm = make_float2(zex3 - zo3y, zey3 + zo3x);
        Z[k] = zk;
        if (k != 0 && k != 2048) Z[MFFT - k] = zm;
    }
    __syncthreads();

    fft_core(Z, tid, -1.0f);          // inverse (unnormalized)

    const float invM = 1.0f / (float)MFFT;
    for (int m = tid; m < MFFT; m += 256) {
        const float2 z = Z[m];
        *(float2*)&row[2 * m] = make_float2(z.x * invM, z.y * invM);
    }
}

// ---------------- K3: transpose back * filt_w, LN2, cast bf16 --------------
__global__ __launch_bounds__(256) void k3_filt_ln2(const float* __restrict__ ht,
                                                   const float* __restrict__ fw,
                                                   const float* __restrict__ g2,
                                                   const float* __restrict__ b2,
                                                   bf16* __restrict__ aln) {
    __shared__ float tile[DDIM][33];
    const int tid  = threadIdx.x;
    const int wave = tid >> 6, lane = tid & 63;
    const int b  = blockIdx.x >> 8;
    const int l0 = (blockIdx.x & 255) << 5;
    for (int i = tid; i < DDIM * 32; i += 256) {
        const int d = i >> 5, ll = i & 31;
        tile[d][ll] = ht[(b * DDIM + d) * LSEQ + l0 + ll];
    }
    __syncthreads();
    const float4 g4 = *(const float4*)&g2[lane * 4];
    const float4 bb4 = *(const float4*)&b2[lane * 4];
    for (int r8 = 0; r8 < 8; ++r8) {
        const int l = r8 * 4 + wave;
        const int gl = l0 + l;
        const float4 f4 = *(const float4*)&fw[gl * DDIM + lane * 4];
        float v[4];
        v[0] = tile[lane * 4 + 0][l] * f4.x;
        v[1] = tile[lane * 4 + 1][l] * f4.y;
        v[2] = tile[lane * 4 + 2][l] * f4.z;
        v[3] = tile[lane * 4 + 3][l] * f4.w;
        float s = v[0] + v[1] + v[2] + v[3];
        float q = v[0] * v[0] + v[1] * v[1] + v[2] * v[2] + v[3] * v[3];
        wave_reduce2(s, q);
        const float mean = s * (1.0f / 256.0f);
        const float var  = q * (1.0f / 256.0f) - mean * mean;
        const float rstd = rsqrtf(var + 1e-5f);
        const float gg[4] = {g4.x, g4.y, g4.z, g4.w};
        const float bb[4] = {bb4.x, bb4.y, bb4.z, bb4.w};
        bf16x4 o;
        #pragma unroll
        for (int j = 0; j < 4; ++j)
            o[j] = (bf16)((v[j] - mean) * rstd * gg[j] + bb[j]);
        *(bf16x4*)&aln[(b * LSEQ + gl) * DDIM + lane * 4] = o;
    }
}

// ---------------- K4: fused MLP, 128-row tiles, reg-resident A -------------
// LDS: W1 strip [64][256] bf16 @0 (32KB), W2 strip [256][64] bf16 @32768 (32KB),
//      lM [128][64] bf16 @65536 (16KB)  => 80KB total.
// All LDS tiles XOR-swizzled: byte_in_row ^= (row&7)<<4  (G4 fix for
// 512B/128B row strides == bank 0). Staged via global_load_lds with
// inverse-swizzled global source (rule 21).
#define LDS_W1 0
#define LDS_W2 32768
#define LDS_LM 65536
#define LDS_TOT 81920

__global__ __launch_bounds__(512, 2) void k4_mlp(const bf16* __restrict__ aln,
                                                 const bf16* __restrict__ w1t,
                                                 const bf16* __restrict__ w2ct,
                                                 const float* __restrict__ bb1,
                                                 const float* __restrict__ bb2,
                                                 const float* __restrict__ x,
                                                 float* __restrict__ out) {
    extern __shared__ char sm[];
    const int tid = threadIdx.x;
    const int lane = tid & 63, w = tid >> 6;
    const int rowLane = lane & 15, grp = lane >> 4;
    const int wm = w >> 1, wn = w & 1;        // 4M x 2N wave grid
    const int row0 = blockIdx.x << 7;         // 128 rows per block
    const int sw = (rowLane & 7) << 4;        // row-XOR for rowLane-indexed rows

    // A fragments: wave's 32x256 slice of aln, direct from global (coalesced:
    // 4 grp x 16 rows cover full 64B lines). 64 VGPRs, live whole kernel.
    bf16x8 aF[2][8];
    #pragma unroll
    for (int fm = 0; fm < 2; ++fm) {
        const size_t rb = (size_t)(row0 + wm * 32 + fm * 16 + rowLane) * DDIM;
        #pragma unroll
        for (int ks = 0; ks < 8; ++ks)
            aF[fm][ks] = *(const bf16x8*)(aln + rb + ks * 32 + grp * 8);
    }
    // prologue: stage W1 chunk 0
    {
        const char* g1 = (const char*)w1t;
        #pragma unroll
        for (int r = 0; r < 4; ++r) {
            const int o = r * 8192 + tid * 16;
            gl_lds16(g1 + (o ^ (((o >> 9) & 7) << 4)), sm + LDS_W1 + o);
        }
    }
    __syncthreads();

    f32x4 acc[2][8];
    #pragma unroll
    for (int i = 0; i < 2; ++i)
        #pragma unroll
        for (int j2 = 0; j2 < 8; ++j2) acc[i][j2] = (f32x4){0.f, 0.f, 0.f, 0.f};

    for (int c = 0; c < 16; ++c) {
        // stage W2 chunk c (w2buf free: G2(c-1) done before last barrier)
        {
            const char* g2 = (const char*)(w2ct + (size_t)c * DDIM * 64);
            #pragma unroll
            for (int r = 0; r < 4; ++r) {
                const int o = r * 8192 + tid * 16;
                gl_lds16(g2 + (o ^ (((o >> 7) & 7) << 4)), sm + LDS_W2 + o);
            }
        }
        const float bias0 = bb1[c * 64 + wn * 32 + rowLane];
        const float bias1 = bb1[c * 64 + wn * 32 + 16 + rowLane];

        // ---- GEMM1: P(32x32/wave) = Areg(32x256) x W1c; A reused from regs
        f32x4 p00 = {0.f,0.f,0.f,0.f}, p01 = p00, p10 = p00, p11 = p00;
        const int hc0 = wn * 32 + rowLane;
        #pragma unroll
        for (int ks = 0; ks < 8; ++ks) {
            const int kb = (ks * 64 + grp * 16) ^ sw;
            const bf16x8 b0 = *(const bf16x8*)(sm + LDS_W1 + hc0 * 512 + kb);
            const bf16x8 b1 = *(const bf16x8*)(sm + LDS_W1 + (hc0 + 16) * 512 + kb);
            p00 = __builtin_amdgcn_mfma_f32_16x16x32_bf16(aF[0][ks], b0, p00, 0, 0, 0);
            p10 = __builtin_amdgcn_mfma_f32_16x16x32_bf16(aF[1][ks], b0, p10, 0, 0, 0);
            p01 = __builtin_amdgcn_mfma_f32_16x16x32_bf16(aF[0][ks], b1, p01, 0, 0, 0);
            p11 = __builtin_amdgcn_mfma_f32_16x16x32_bf16(aF[1][ks], b1, p11, 0, 0, 0);
        }
        // ---- bias + exact gelu -> lM (swizzled b16 writes)
        #pragma unroll
        for (int fm = 0; fm < 2; ++fm)
        #pragma unroll
        for (int fn = 0; fn < 2; ++fn) {
            const f32x4 pv = fm ? (fn ? p11 : p10) : (fn ? p01 : p00);
            const int pcol2 = (wn * 32 + fn * 16 + rowLane) * 2;
            const float bias = fn ? bias1 : bias0;
            #pragma unroll
            for (int j = 0; j < 4; ++j) {
                const int prow = wm * 32 + fm * 16 + grp * 4 + j;
                const float v = pv[j] + bias;
                const float ge = 0.5f * v * (1.0f + erff(v * 0.70710678118654752f));
                *(bf16*)(sm + LDS_LM + prow * 128 + (pcol2 ^ ((prow & 7) << 4))) = (bf16)ge;
            }
        }
        __syncthreads();   // lM visible; W2 staging drained; G1 done with w1buf
        // stage W1 chunk c+1 under G2's cover (w1buf readers all pre-barrier)
        if (c < 15) {
            const char* g1 = (const char*)(w1t + (size_t)(c + 1) * 64 * DDIM);
            #pragma unroll
            for (int r = 0; r < 4; ++r) {
                const int o = r * 8192 + tid * 16;
                gl_lds16(g1 + (o ^ (((o >> 9) & 7) << 4)), sm + LDS_W1 + o);
            }
        }
        // ---- GEMM2: acc(32x128/wave) += lM(32x64) x W2c(64->128 cols)
        const int ar0 = wm * 32 + rowLane;
        #pragma unroll
        for (int kk = 0; kk < 2; ++kk) {
            const int kb = (kk * 64 + grp * 16) ^ sw;
            const bf16x8 a0 = *(const bf16x8*)(sm + LDS_LM + ar0 * 128 + kb);
            const bf16x8 a1 = *(const bf16x8*)(sm + LDS_LM + (ar0 + 16) * 128 + kb);
            #pragma unroll
            for (int fn = 0; fn < 8; ++fn) {
                const int dcol = wn * 128 + fn * 16 + rowLane;
                const bf16x8 bw = *(const bf16x8*)(sm + LDS_W2 + dcol * 128 + kb);
                acc[0][fn] = __builtin_amdgcn_mfma_f32_16x16x32_bf16(a0, bw, acc[0][fn], 0, 0, 0);
                acc[1][fn] = __builtin_amdgcn_mfma_f32_16x16x32_bf16(a1, bw, acc[1][fn], 0, 0, 0);
            }
        }
        __syncthreads();   // G2 done with lM/w2buf; W1 staging drained
    }
    // ---- epilogue: +bb2 + residual
    #pragma unroll
    for (int fn = 0; fn < 8; ++fn) {
        const int dcol = wn * 128 + fn * 16 + rowLane;
        const float b2v = bb2[dcol];
        #pragma unroll
        for (int fm = 0; fm < 2; ++fm)
        #pragma unroll
        for (int j = 0; j < 4; ++j) {
            const int orow = row0 + wm * 32 + fm * 16 + grp * 4 + j;
            const int gi = orow * DDIM + dcol;
            out[gi] = acc[fm][fn][j] + b2v + x[gi];
        }
    }
}

extern "C" void kernel_launch(void* const* d_in, const int* in_sizes, int n_in,
                              void* d_out, int out_size, void* d_ws, size_t ws_size,
                              hipStream_t stream) {
    (void)in_sizes; (void)n_in; (void)out_size; (void)ws_size;
    const float* x   = (const float*)d_in[0];
    const float* g1  = (const float*)d_in[1];
    const float* b1  = (const float*)d_in[2];
    const float* g2  = (const float*)d_in[3];
    const float* b2  = (const float*)d_in[4];
    const float* fw  = (const float*)d_in[5];
    const float* w1  = (const float*)d_in[6];
    const float* bb1 = (const float*)d_in[7];
    const float* w2  = (const float*)d_in[8];
    const float* bb2 = (const float*)d_in[9];
    float* out = (float*)d_out;
    char*  ws  = (char*)d_ws;

    bf16* aln  = (bf16*)ws;                              // 33554432 B
    bf16* w1t  = (bf16*)(ws + (size_t)33554432);         //   524288 B
    bf16* w2ct = (bf16*)(ws + (size_t)34078720);         //   524288 B
    float* ht = out;                                     // reuse d_out as (B,D,L) scratch

    k0_prep<<<dim3(1024), dim3(256), 0, stream>>>(w1, w2, w1t, w2ct);
    k1_ln1_relu_T<<<dim3(2048), dim3(256), 0, stream>>>(x, g1, b1, ht);
    k2_spsd<<<dim3(2048), dim3(256), 0, stream>>>(ht);
    k3_filt_ln2<<<dim3(2048), dim3(256), 0, stream>>>(ht, fw, g2, b2, aln);
    k4_mlp<<<dim3(512), dim3(512), LDS_TOT, stream>>>(aln, w1t, w2ct, bb1, bb2, x, out);
}

// Round 3
// 270.617 us; speedup vs baseline: 1.4759x; 1.1663x over previous
//
#include <hip/hip_runtime.h>
#include <hip/hip_bf16.h>

#define BSZ  8
#define LSEQ 8192
#define DDIM 256
#define HDIM 1024
#define MFFT 4096   // half-size complex FFT length (N = 8192 real)

typedef __bf16 bf16;
typedef __bf16 bf16x8 __attribute__((ext_vector_type(8)));
typedef __bf16 bf16x4 __attribute__((ext_vector_type(4)));
typedef float  f32x4  __attribute__((ext_vector_type(4)));

__device__ __forceinline__ void wave_reduce2(float& a, float& b) {
    #pragma unroll
    for (int off = 1; off < 64; off <<= 1) {
        a += __shfl_xor(a, off);
        b += __shfl_xor(b, off);
    }
}

// async global->LDS 16B; LDS dest = wave-uniform base + lane*16 (linear).
__device__ __forceinline__ void gl_lds16(const void* g, void* l) {
    __builtin_amdgcn_global_load_lds(
        (const __attribute__((address_space(1))) unsigned int*)(unsigned long long)g,
        (__attribute__((address_space(3))) unsigned int*)(unsigned int)(unsigned long long)l,
        16, 0, 0);
}

// ---------------- K0: bf16 weights: W1T[h][d]; W2C chunk-major [c][d][hh] ---
__global__ __launch_bounds__(256) void k0_prep(const float* __restrict__ w1,
                                               const float* __restrict__ w2,
                                               bf16* __restrict__ w1t,
                                               bf16* __restrict__ w2ct) {
    const int e = blockIdx.x * 256 + threadIdx.x;   // 0..262143
    {   // W1T[h][d] = w1[d][h]
        const int h = e >> 8, d = e & 255;
        w1t[e] = (bf16)w1[d * HDIM + h];
    }
    {   // W2C[c][d][hh] = w2[c*64+hh][d]
        const int hh = e & 63, d = (e >> 6) & 255, c = e >> 14;
        w2ct[e] = (bf16)w2[(c * 64 + hh) * DDIM + d];
    }
}

// ---------------- K1: LN1 + ReLU + eps, transposed write: ht(B,D,L) --------
__global__ __launch_bounds__(256) void k1_ln1_relu_T(const float* __restrict__ x,
                                                     const float* __restrict__ g1,
                                                     const float* __restrict__ b1,
                                                     float* __restrict__ ht) {
    __shared__ float tile[DDIM][33];   // [d][l] padded
    const int tid  = threadIdx.x;
    const int wave = tid >> 6, lane = tid & 63;
    const int b  = blockIdx.x >> 8;           // 256 l-tiles per batch
    const int l0 = (blockIdx.x & 255) << 5;
    const float4 g4 = *(const float4*)&g1[lane * 4];
    const float4 b4 = *(const float4*)&b1[lane * 4];
    for (int r8 = 0; r8 < 8; ++r8) {
        const int l = r8 * 4 + wave;
        const float4 v = *(const float4*)&x[(b * LSEQ + l0 + l) * DDIM + lane * 4];
        float s = v.x + v.y + v.z + v.w;
        float q = v.x * v.x + v.y * v.y + v.z * v.z + v.w * v.w;
        wave_reduce2(s, q);
        const float mean = s * (1.0f / 256.0f);
        const float var  = q * (1.0f / 256.0f) - mean * mean;
        const float rstd = rsqrtf(var + 1e-5f);
        const float vv[4] = {v.x, v.y, v.z, v.w};
        const float gg[4] = {g4.x, g4.y, g4.z, g4.w};
        const float bb[4] = {b4.x, b4.y, b4.z, b4.w};
        #pragma unroll
        for (int j = 0; j < 4; ++j) {
            float t = (vv[j] - mean) * rstd * gg[j] + bb[j];
            t = fmaxf(t, 0.0f) + 1e-6f;
            tile[lane * 4 + j][l] = t;
        }
    }
    __syncthreads();
    for (int i = tid; i < DDIM * 32; i += 256) {
        const int d = i >> 5, ll = i & 31;
        ht[(b * DDIM + d) * LSEQ + l0 + ll] = tile[d][ll];
    }
}

// ---------------- K2: per-channel SPSD1D, radix-4 + twiddle LUT ------------
// Z physical layout XOR-swizzled (point-level, float2 units): zs(p)=p^((p>>4)&15)
__device__ __forceinline__ int zs(int p) { return p ^ ((p >> 4) & 15); }
__device__ __forceinline__ float2 cmul(float2 a, float2 b) {
    return make_float2(a.x * b.x - a.y * b.y, a.x * b.y + a.y * b.x);
}

// per-stage tw1 tables, stage s has q=1024>>2s entries at OFF4[s]
__device__ __constant__ int OFF4[6] = {0, 1024, 1280, 1344, 1360, 1364};

__device__ __forceinline__ void build_lut(float2* lut, int tid) {
    #pragma unroll
    for (int s = 0; s < 6; ++s) {
        const int q = 1024 >> (2 * s), off = OFF4[s];
        for (int j = tid; j < q; j += 512) {
            float sn, cs;   // W_m^j = e^{-2pi i j / m}, m = 4096>>2s
            __sincosf(-6.283185307179586f * (float)(j << (2 * s)) * (1.0f / 4096.0f), &sn, &cs);
            lut[off + j] = make_float2(cs, sn);
        }
    }
}

template<int DIR>   // +1 forward, -1 inverse (unnormalized)
__device__ __forceinline__ void fft_r4(float2* Z, const float2* lut, int tid) {
    #pragma unroll
    for (int s = 0; s < 6; ++s) {
        const int lq = 10 - 2 * s;
        const int q  = 1 << lq;
        const int off = OFF4[s];
        #pragma unroll
        for (int it = 0; it < 2; ++it) {
            const int i = tid + (it << 9);                    // butterfly 0..1023
            const int j = i & (q - 1);
            const int base = ((i >> lq) << (lq + 2)) + j;     // blk*m + j
            float2 a = Z[zs(base)];
            float2 b = Z[zs(base + q)];
            float2 c = Z[zs(base + 2 * q)];
            float2 d = Z[zs(base + 3 * q)];
            float2 w1 = lut[off + j];
            if (DIR < 0) w1.y = -w1.y;
            const float2 w2 = cmul(w1, w1);
            const float2 w3 = cmul(w1, w2);
            const float2 t0 = make_float2(a.x + c.x, a.y + c.y);
            const float2 t1 = make_float2(a.x - c.x, a.y - c.y);
            const float2 t2 = make_float2(b.x + d.x, b.y + d.y);
            const float2 t3 = make_float2(b.x - d.x, b.y - d.y);
            const float2 y0 = make_float2(t0.x + t2.x, t0.y + t2.y);
            const float2 y2 = make_float2(t0.x - t2.x, t0.y - t2.y);
            float2 y1, y3;
            if (DIR > 0) {   // y1 = t1 - i*t3 ; y3 = t1 + i*t3
                y1 = make_float2(t1.x + t3.y, t1.y - t3.x);
                y3 = make_float2(t1.x - t3.y, t1.y + t3.x);
            } else {
                y1 = make_float2(t1.x - t3.y, t1.y + t3.x);
                y3 = make_float2(t1.x + t3.y, t1.y - t3.x);
            }
            Z[zs(base)]         = y0;
            Z[zs(base + q)]     = cmul(y1, w1);
            Z[zs(base + 2 * q)] = cmul(y2, w2);
            Z[zs(base + 3 * q)] = cmul(y3, w3);
        }
        __syncthreads();
    }
    // base-4 digit reversal (12-bit): bitrev then swap adjacent bit pairs
    for (int idx = tid; idx < MFFT; idx += 512) {
        const unsigned br = __brev((unsigned)idx) >> 20;
        const unsigned r4 = ((br & 0x555u) << 1) | ((br >> 1) & 0x555u);
        if (r4 > (unsigned)idx) {
            const int pa = zs(idx), pb = zs((int)r4);
            const float2 t = Z[pa]; Z[pa] = Z[pb]; Z[pb] = t;
        }
    }
    __syncthreads();
}

__global__ __launch_bounds__(512, 4) void k2_spsd(float* __restrict__ ht) {
    __shared__ float2 Z[MFFT];        // 32 KB, swizzled
    __shared__ float  mg[MFFT + 8];   // 16.4 KB: mag[] / twiddle-LUT union
    float2* lut = (float2*)mg;
    const int tid = threadIdx.x;
    float* row = ht + (size_t)blockIdx.x * LSEQ;

    for (int m = tid; m < MFFT; m += 512)
        Z[zs(m)] = *(const float2*)&row[2 * m];
    build_lut(lut, tid);
    __syncthreads();

    fft_r4<1>(Z, lut, tid);           // forward FFT of packed even+i*odd

    // Pass A: magnitudes of rfft bins 0..4096 (lut dead after this)
    for (int k = tid; k <= MFFT; k += 512) {
        const int ka = k & (MFFT - 1);
        const int kb = (MFFT - k) & (MFFT - 1);
        const float2 A = Z[zs(ka)], Bc = Z[zs(kb)];
        const float zex = 0.5f * (A.x + Bc.x), zey = 0.5f * (A.y - Bc.y);
        const float zox = 0.5f * (A.y + Bc.y), zoy = -0.5f * (A.x - Bc.x);
        float sn, cs;   // e^{-i pi k/4096} = (cs, sn)
        __sincosf((float)k * (-3.14159265358979323846f / 4096.0f), &sn, &cs);
        const float xr = zex + zox * cs - zoy * sn;
        const float xi = zey + zox * sn + zoy * cs;
        mg[k] = sqrtf(xr * xr + xi * xi);
    }
    __syncthreads();

    // Pass B: mask + rebuild filtered half-spectrum, in place (pairs disjoint)
    for (int k = tid; k <= 2048; k += 512) {
        const int km = (MFFT - k) & (MFFT - 1);
        const float2 Pk = Z[zs(k)];
        const float2 Pm = Z[zs(km)];
        float sn, cs;   // theta = pi k/4096
        __sincosf((float)k * (3.14159265358979323846f / 4096.0f), &sn, &cs);
        // bin k:  W = (cs,-sn)
        const float zex = 0.5f * (Pk.x + Pm.x), zey = 0.5f * (Pk.y - Pm.y);
        const float zox = 0.5f * (Pk.y + Pm.y), zoy = -0.5f * (Pk.x - Pm.x);
        float xkr = zex + zox * cs + zoy * sn;
        float xki = zey - zox * sn + zoy * cs;
        // bin 4096-k:  A'=Pm, B'=conj(Pk), W = (-cs,-sn)
        const float zex2 = 0.5f * (Pm.x + Pk.x), zey2 = 0.5f * (Pm.y - Pk.y);
        const float zox2 = 0.5f * (Pm.y + Pk.y), zoy2 = -0.5f * (Pm.x - Pk.x);
        float xmr = zex2 - zox2 * cs + zoy2 * sn;
        float xmi = zey2 - zox2 * sn - zoy2 * cs;
        // keep masks: local max over window [j-3, j+4] (clamped), or j < 3
        const int jm = MFFT - k;
        bool keepk, keepm;
        {
            const int lo = (k - 3 < 0) ? 0 : k - 3;
            const int hi = (k + 4 > 4096) ? 4096 : k + 4;
            float mx = mg[k];
            for (int t2 = lo; t2 <= hi; ++t2) mx = fmaxf(mx, mg[t2]);
            keepk = (k < 3) || (mg[k] >= mx);
        }
        {
            const int hi = (jm + 4 > 4096) ? 4096 : jm + 4;
            float mx = mg[jm];
            for (int t2 = jm - 3; t2 <= hi; ++t2) mx = fmaxf(mx, mg[t2]);
            keepm = (mg[jm] >= mx);
        }
        if (!keepk) { xkr = 0.0f; xki = 0.0f; }
        if (!keepm) { xmr = 0.0f; xmi = 0.0f; }
        // Z'f[k] = Ze' + i Zo';  Ze' = (X'k + conj(X'm))/2,  Zo' = (cs,sn)*(X'k - conj(X'm))/2
        const float zpex = 0.5f * (xkr + xmr), zpey = 0.5f * (xki - xmi);
        const float dfx  = 0.5f * (xkr - xmr), dfy  = 0.5f * (xki + xmi);
        const float zpox = dfx * cs - dfy * sn, zpoy = dfx * sn + dfy * cs;
        const float2 zk = make_float2(zpex - zpoy, zpey + zpox);
        // Z'f[4096-k]:  t = (-cs, sn)
        const float zex3 = 0.5f * (xmr + xkr), zey3 = 0.5f * (xmi - xki);
        const float df2x = 0.5f * (xmr - xkr), df2y = 0.5f * (xmi + xki);
        const float zo3x = -df2x * cs - df2y * sn, zo3y = df2x * sn - df2y * cs;
        const float2 zm = make_float2(zex3 - zo3y, zey3 + zo3x);
        Z[zs(k)] = zk;
        if (k != 0 && k != 2048) Z[zs(MFFT - k)] = zm;
    }
    __syncthreads();

    build_lut(lut, tid);              // mag dead; rebuild twiddles for inverse
    __syncthreads();

    fft_r4<-1>(Z, lut, tid);          // inverse (unnormalized)

    const float invM = 1.0f / (float)MFFT;
    for (int m = tid; m < MFFT; m += 512) {
        const float2 z = Z[zs(m)];
        *(float2*)&row[2 * m] = make_float2(z.x * invM, z.y * invM);
    }
}

// ---------------- K3: transpose back * filt_w, LN2, cast bf16 --------------
__global__ __launch_bounds__(256) void k3_filt_ln2(const float* __restrict__ ht,
                                                   const float* __restrict__ fw,
                                                   const float* __restrict__ g2,
                                                   const float* __restrict__ b2,
                                                   bf16* __restrict__ aln) {
    __shared__ float tile[DDIM][33];
    const int tid  = threadIdx.x;
    const int wave = tid >> 6, lane = tid & 63;
    const int b  = blockIdx.x >> 8;
    const int l0 = (blockIdx.x & 255) << 5;
    for (int i = tid; i < DDIM * 32; i += 256) {
        const int d = i >> 5, ll = i & 31;
        tile[d][ll] = ht[(b * DDIM + d) * LSEQ + l0 + ll];
    }
    __syncthreads();
    const float4 g4 = *(const float4*)&g2[lane * 4];
    const float4 bb4 = *(const float4*)&b2[lane * 4];
    for (int r8 = 0; r8 < 8; ++r8) {
        const int l = r8 * 4 + wave;
        const int gl = l0 + l;
        const float4 f4 = *(const float4*)&fw[gl * DDIM + lane * 4];
        float v[4];
        v[0] = tile[lane * 4 + 0][l] * f4.x;
        v[1] = tile[lane * 4 + 1][l] * f4.y;
        v[2] = tile[lane * 4 + 2][l] * f4.z;
        v[3] = tile[lane * 4 + 3][l] * f4.w;
        float s = v[0] + v[1] + v[2] + v[3];
        float q = v[0] * v[0] + v[1] * v[1] + v[2] * v[2] + v[3] * v[3];
        wave_reduce2(s, q);
        const float mean = s * (1.0f / 256.0f);
        const float var  = q * (1.0f / 256.0f) - mean * mean;
        const float rstd = rsqrtf(var + 1e-5f);
        const float gg[4] = {g4.x, g4.y, g4.z, g4.w};
        const float bb[4] = {bb4.x, bb4.y, bb4.z, bb4.w};
        bf16x4 o;
        #pragma unroll
        for (int j = 0; j < 4; ++j)
            o[j] = (bf16)((v[j] - mean) * rstd * gg[j] + bb[j]);
        *(bf16x4*)&aln[(b * LSEQ + gl) * DDIM + lane * 4] = o;
    }
}

// ---------------- K4: fused MLP, 128-row tiles, reg-resident A -------------
#define LDS_W1 0
#define LDS_W2 32768
#define LDS_LM 65536
#define LDS_TOT 81920

__global__ __launch_bounds__(512, 2) void k4_mlp(const bf16* __restrict__ aln,
                                                 const bf16* __restrict__ w1t,
                                                 const bf16* __restrict__ w2ct,
                                                 const float* __restrict__ bb1,
                                                 const float* __restrict__ bb2,
                                                 const float* __restrict__ x,
                                                 float* __restrict__ out) {
    extern __shared__ char sm[];
    const int tid = threadIdx.x;
    const int lane = tid & 63, w = tid >> 6;
    const int rowLane = lane & 15, grp = lane >> 4;
    const int wm = w >> 1, wn = w & 1;        // 4M x 2N wave grid
    const int row0 = blockIdx.x << 7;         // 128 rows per block
    const int sw = (rowLane & 7) << 4;        // row-XOR for rowLane-indexed rows

    bf16x8 aF[2][8];
    #pragma unroll
    for (int fm = 0; fm < 2; ++fm) {
        const size_t rb = (size_t)(row0 + wm * 32 + fm * 16 + rowLane) * DDIM;
        #pragma unroll
        for (int ks = 0; ks < 8; ++ks)
            aF[fm][ks] = *(const bf16x8*)(aln + rb + ks * 32 + grp * 8);
    }
    {
        const char* g1 = (const char*)w1t;
        #pragma unroll
        for (int r = 0; r < 4; ++r) {
            const int o = r * 8192 + tid * 16;
            gl_lds16(g1 + (o ^ (((o >> 9) & 7) << 4)), sm + LDS_W1 + o);
        }
    }
    __syncthreads();

    f32x4 acc[2][8];
    #pragma unroll
    for (int i = 0; i < 2; ++i)
        #pragma unroll
        for (int j2 = 0; j2 < 8; ++j2) acc[i][j2] = (f32x4){0.f, 0.f, 0.f, 0.f};

    for (int c = 0; c < 16; ++c) {
        {
            const char* g2 = (const char*)(w2ct + (size_t)c * DDIM * 64);
            #pragma unroll
            for (int r = 0; r < 4; ++r) {
                const int o = r * 8192 + tid * 16;
                gl_lds16(g2 + (o ^ (((o >> 7) & 7) << 4)), sm + LDS_W2 + o);
            }
        }
        const float bias0 = bb1[c * 64 + wn * 32 + rowLane];
        const float bias1 = bb1[c * 64 + wn * 32 + 16 + rowLane];

        f32x4 p00 = {0.f,0.f,0.f,0.f}, p01 = p00, p10 = p00, p11 = p00;
        const int hc0 = wn * 32 + rowLane;
        #pragma unroll
        for (int ks = 0; ks < 8; ++ks) {
            const int kb = (ks * 64 + grp * 16) ^ sw;
            const bf16x8 b0 = *(const bf16x8*)(sm + LDS_W1 + hc0 * 512 + kb);
            const bf16x8 b1 = *(const bf16x8*)(sm + LDS_W1 + (hc0 + 16) * 512 + kb);
            p00 = __builtin_amdgcn_mfma_f32_16x16x32_bf16(aF[0][ks], b0, p00, 0, 0, 0);
            p10 = __builtin_amdgcn_mfma_f32_16x16x32_bf16(aF[1][ks], b0, p10, 0, 0, 0);
            p01 = __builtin_amdgcn_mfma_f32_16x16x32_bf16(aF[0][ks], b1, p01, 0, 0, 0);
            p11 = __builtin_amdgcn_mfma_f32_16x16x32_bf16(aF[1][ks], b1, p11, 0, 0, 0);
        }
        #pragma unroll
        for (int fm = 0; fm < 2; ++fm)
        #pragma unroll
        for (int fn = 0; fn < 2; ++fn) {
            const f32x4 pv = fm ? (fn ? p11 : p10) : (fn ? p01 : p00);
            const int pcol2 = (wn * 32 + fn * 16 + rowLane) * 2;
            const float bias = fn ? bias1 : bias0;
            #pragma unroll
            for (int j = 0; j < 4; ++j) {
                const int prow = wm * 32 + fm * 16 + grp * 4 + j;
                const float v = pv[j] + bias;
                const float ge = 0.5f * v * (1.0f + erff(v * 0.70710678118654752f));
                *(bf16*)(sm + LDS_LM + prow * 128 + (pcol2 ^ ((prow & 7) << 4))) = (bf16)ge;
            }
        }
        __syncthreads();
        if (c < 15) {
            const char* g1 = (const char*)(w1t + (size_t)(c + 1) * 64 * DDIM);
            #pragma unroll
            for (int r = 0; r < 4; ++r) {
                const int o = r * 8192 + tid * 16;
                gl_lds16(g1 + (o ^ (((o >> 9) & 7) << 4)), sm + LDS_W1 + o);
            }
        }
        const int ar0 = wm * 32 + rowLane;
        #pragma unroll
        for (int kk = 0; kk < 2; ++kk) {
            const int kb = (kk * 64 + grp * 16) ^ sw;
            const bf16x8 a0 = *(const bf16x8*)(sm + LDS_LM + ar0 * 128 + kb);
            const bf16x8 a1 = *(const bf16x8*)(sm + LDS_LM + (ar0 + 16) * 128 + kb);
            #pragma unroll
            for (int fn = 0; fn < 8; ++fn) {
                const int dcol = wn * 128 + fn * 16 + rowLane;
                const bf16x8 bw = *(const bf16x8*)(sm + LDS_W2 + dcol * 128 + kb);
                acc[0][fn] = __builtin_amdgcn_mfma_f32_16x16x32_bf16(a0, bw, acc[0][fn], 0, 0, 0);
                acc[1][fn] = __builtin_amdgcn_mfma_f32_16x16x32_bf16(a1, bw, acc[1][fn], 0, 0, 0);
            }
        }
        __syncthreads();
    }
    #pragma unroll
    for (int fn = 0; fn < 8; ++fn) {
        const int dcol = wn * 128 + fn * 16 + rowLane;
        const float b2v = bb2[dcol];
        #pragma unroll
        for (int fm = 0; fm < 2; ++fm)
        #pragma unroll
        for (int j = 0; j < 4; ++j) {
            const int orow = row0 + wm * 32 + fm * 16 + grp * 4 + j;
            const int gi = orow * DDIM + dcol;
            out[gi] = acc[fm][fn][j] + b2v + x[gi];
        }
    }
}

extern "C" void kernel_launch(void* const* d_in, const int* in_sizes, int n_in,
                              void* d_out, int out_size, void* d_ws, size_t ws_size,
                              hipStream_t stream) {
    (void)in_sizes; (void)n_in; (void)out_size; (void)ws_size;
    const float* x   = (const float*)d_in[0];
    const float* g1  = (const float*)d_in[1];
    const float* b1  = (const float*)d_in[2];
    const float* g2  = (const float*)d_in[3];
    const float* b2  = (const float*)d_in[4];
    const float* fw  = (const float*)d_in[5];
    const float* w1  = (const float*)d_in[6];
    const float* bb1 = (const float*)d_in[7];
    const float* w2  = (const float*)d_in[8];
    const float* bb2 = (const float*)d_in[9];
    float* out = (float*)d_out;
    char*  ws  = (char*)d_ws;

    bf16* aln  = (bf16*)ws;                              // 33554432 B
    bf16* w1t  = (bf16*)(ws + (size_t)33554432);         //   524288 B
    bf16* w2ct = (bf16*)(ws + (size_t)34078720);         //   524288 B
    float* ht = out;                                     // reuse d_out as (B,D,L) scratch

    k0_prep<<<dim3(1024), dim3(256), 0, stream>>>(w1, w2, w1t, w2ct);
    k1_ln1_relu_T<<<dim3(2048), dim3(256), 0, stream>>>(x, g1, b1, ht);
    k2_spsd<<<dim3(2048), dim3(512), 0, stream>>>(ht);
    k3_filt_ln2<<<dim3(2048), dim3(256), 0, stream>>>(ht, fw, g2, b2, aln);
    k4_mlp<<<dim3(512), dim3(512), LDS_TOT, stream>>>(aln, w1t, w2ct, bb1, bb2, x, out);
}